// Round 1
// baseline (4960.682 us; speedup 1.0000x reference)
//
#include <hip/hip_runtime.h>
#include <hip/hip_bf16.h>

#define NTOK 8192
#define SCC  16
#define CD   128
#define WD   512
#define OD   1024
#define ED   640   // WD + CD

// ---------------------------------------------------------------------------
// Kernel 1: per-token gated pyramid scan.
// One workgroup (256 threads) per token. State S (16x128 f32) lives in LDS.
// Per step (A = L - length active rows):
//   dot phase: each thread owns weight rows o0=2*tid, o1=2*tid+1 (Wg rows
//   0..383, then Wp rows 0..127), streams them from L2, and accumulates A dot
//   products against flat_p = S + p*128 (contiguous 256 floats = [left|right]).
//   combine phase: softmax over the 3 gate chunks + convex combine, write back.
// ---------------------------------------------------------------------------

template<int A>
__device__ __forceinline__ void dot_phase(const float* __restrict__ w0,
                                          const float* __restrict__ w1,
                                          float b0, float b1,
                                          const float* S, float* G, int tid)
{
    float acc0[A], acc1[A];
#pragma unroll
    for (int p = 0; p < A; ++p) { acc0[p] = 0.f; acc1[p] = 0.f; }
#pragma unroll 2
    for (int kc = 0; kc < 64; ++kc) {
        const int k = kc * 4;
        const float4 wa = *reinterpret_cast<const float4*>(w0 + k);
        const float4 wb = *reinterpret_cast<const float4*>(w1 + k);
#pragma unroll
        for (int p = 0; p < A; ++p) {
            const float4 f = *reinterpret_cast<const float4*>(S + p * CD + k);
            acc0[p] = fmaf(wa.x, f.x, acc0[p]);
            acc0[p] = fmaf(wa.y, f.y, acc0[p]);
            acc0[p] = fmaf(wa.z, f.z, acc0[p]);
            acc0[p] = fmaf(wa.w, f.w, acc0[p]);
            acc1[p] = fmaf(wb.x, f.x, acc1[p]);
            acc1[p] = fmaf(wb.y, f.y, acc1[p]);
            acc1[p] = fmaf(wb.z, f.z, acc1[p]);
            acc1[p] = fmaf(wb.w, f.w, acc1[p]);
        }
    }
#pragma unroll
    for (int p = 0; p < A; ++p) {
        G[p * 512 + 2 * tid]     = acc0[p] + b0;
        G[p * 512 + 2 * tid + 1] = acc1[p] + b1;
    }
}

__global__ __launch_bounds__(256) void scan_kernel(
    const int*   __restrict__ char_ids,
    const int*   __restrict__ char_lengths,
    const float* __restrict__ char_table,
    const float* __restrict__ Wg, const float* __restrict__ bg,
    const float* __restrict__ Wp, const float* __restrict__ bp,
    float*       __restrict__ char_repr)
{
    __shared__ __align__(16) float S[SCC * CD];   // 8 KB state
    __shared__ __align__(16) float G[15 * 512];   // 30 KB gate/z buffer

    const int t   = blockIdx.x;
    const int tid = threadIdx.x;

    // --- load initial state: S[c][d] = char_table[ids[c]][d] ---
    const int* ids = char_ids + t * SCC;
#pragma unroll
    for (int i = tid; i < SCC * CD; i += 256) {
        const int c = i >> 7, d = i & 127;
        S[i] = char_table[ids[c] * CD + d];
    }

    const int L = char_lengths[t];

    // --- this thread's two weight rows (fixed for all steps) ---
    const int o0 = 2 * tid;
    const int o1 = o0 + 1;
    const float* w0 = (o0 < 384) ? (Wg + o0 * 256) : (Wp + (o0 - 384) * 256);
    const float* w1 = (o1 < 384) ? (Wg + o1 * 256) : (Wp + (o1 - 384) * 256);
    const float  b0 = (o0 < 384) ? bg[o0] : bp[o0 - 384];
    const float  b1 = (o1 < 384) ? bg[o1] : bp[o1 - 384];

    __syncthreads();

    // --- scan: length = 1..L-1  <=>  A = L-1 .. 1 ---
    for (int A = L - 1; A >= 1; --A) {
        switch (A) {
            case  1: dot_phase< 1>(w0, w1, b0, b1, S, G, tid); break;
            case  2: dot_phase< 2>(w0, w1, b0, b1, S, G, tid); break;
            case  3: dot_phase< 3>(w0, w1, b0, b1, S, G, tid); break;
            case  4: dot_phase< 4>(w0, w1, b0, b1, S, G, tid); break;
            case  5: dot_phase< 5>(w0, w1, b0, b1, S, G, tid); break;
            case  6: dot_phase< 6>(w0, w1, b0, b1, S, G, tid); break;
            case  7: dot_phase< 7>(w0, w1, b0, b1, S, G, tid); break;
            case  8: dot_phase< 8>(w0, w1, b0, b1, S, G, tid); break;
            case  9: dot_phase< 9>(w0, w1, b0, b1, S, G, tid); break;
            case 10: dot_phase<10>(w0, w1, b0, b1, S, G, tid); break;
            case 11: dot_phase<11>(w0, w1, b0, b1, S, G, tid); break;
            case 12: dot_phase<12>(w0, w1, b0, b1, S, G, tid); break;
            case 13: dot_phase<13>(w0, w1, b0, b1, S, G, tid); break;
            case 14: dot_phase<14>(w0, w1, b0, b1, S, G, tid); break;
            case 15: dot_phase<15>(w0, w1, b0, b1, S, G, tid); break;
            default: break;
        }
        __syncthreads();

        // --- combine: for each (p,d), softmax over {g0,g1,g2}, convex mix ---
        const int cnt = A * CD;   // <= 1920
        float nv[8];
#pragma unroll
        for (int it = 0; it < 8; ++it) {
            const int idx = tid + it * 256;
            if (idx < cnt) {
                const int p = idx >> 7, d = idx & 127;
                const float g0 = G[p * 512 + d];
                const float g1 = G[p * 512 + 128 + d];
                const float g2 = G[p * 512 + 256 + d];
                const float z  = G[p * 512 + 384 + d];
                const float m  = fmaxf(fmaxf(g0, g1), g2);
                const float e0 = __expf(g0 - m);
                const float e1 = __expf(g1 - m);
                const float e2 = __expf(g2 - m);
                const float left  = S[idx];        // S[p][d]
                const float right = S[idx + CD];   // S[p+1][d]
                nv[it] = (e0 * left + e1 * right + e2 * z) / (e0 + e1 + e2);
            }
        }
        __syncthreads();
#pragma unroll
        for (int it = 0; it < 8; ++it) {
            const int idx = tid + it * 256;
            if (idx < cnt) S[idx] = nv[it];
        }
        __syncthreads();
    }

    // --- char representation = S[0][:] ---
    if (tid < CD) char_repr[t * CD + tid] = S[tid];
}

// ---------------------------------------------------------------------------
// Kernel 2: out[t][j] = b_out[j] + emb[t] . W_out[j]
// emb[t] = [ word_table[word_inputs[t]] (512) | char_repr[t] (128) ]
// 8 tokens per workgroup staged in LDS; each thread owns 4 output columns.
// ---------------------------------------------------------------------------
#define TPB2 8

__global__ __launch_bounds__(256) void out_gemm(
    const int*   __restrict__ word_inputs,
    const float* __restrict__ word_table,
    const float* __restrict__ char_repr,
    const float* __restrict__ W_out,
    const float* __restrict__ b_out,
    float*       __restrict__ out)
{
    __shared__ __align__(16) float E[TPB2 * ED];  // 20 KB

    const int tg  = blockIdx.x * TPB2;
    const int tid = threadIdx.x;

    // stage word parts (TPB2 x 512)
    for (int i = tid; i < TPB2 * WD; i += 256) {
        const int tl = i >> 9, k = i & 511;
        E[tl * ED + k] = word_table[(size_t)word_inputs[tg + tl] * WD + k];
    }
    // stage char parts (TPB2 x 128)
    for (int i = tid; i < TPB2 * CD; i += 256) {
        const int tl = i >> 7, k = i & 127;
        E[tl * ED + WD + k] = char_repr[(tg + tl) * CD + k];
    }
    __syncthreads();

    const int j0 = tid * 4;
    float acc[TPB2][4];
#pragma unroll
    for (int tl = 0; tl < TPB2; ++tl)
#pragma unroll
        for (int jj = 0; jj < 4; ++jj) acc[tl][jj] = 0.f;

#pragma unroll 2
    for (int kc = 0; kc < ED / 4; ++kc) {
        const int k = kc * 4;
        float4 wr[4];
#pragma unroll
        for (int jj = 0; jj < 4; ++jj)
            wr[jj] = *reinterpret_cast<const float4*>(W_out + (size_t)(j0 + jj) * ED + k);
#pragma unroll
        for (int tl = 0; tl < TPB2; ++tl) {
            const float4 e = *reinterpret_cast<const float4*>(E + tl * ED + k);
#pragma unroll
            for (int jj = 0; jj < 4; ++jj) {
                acc[tl][jj] = fmaf(wr[jj].x, e.x, acc[tl][jj]);
                acc[tl][jj] = fmaf(wr[jj].y, e.y, acc[tl][jj]);
                acc[tl][jj] = fmaf(wr[jj].z, e.z, acc[tl][jj]);
                acc[tl][jj] = fmaf(wr[jj].w, e.w, acc[tl][jj]);
            }
        }
    }

    const float4 bb = *reinterpret_cast<const float4*>(b_out + j0);
#pragma unroll
    for (int tl = 0; tl < TPB2; ++tl) {
        float4 r;
        r.x = acc[tl][0] + bb.x;
        r.y = acc[tl][1] + bb.y;
        r.z = acc[tl][2] + bb.z;
        r.w = acc[tl][3] + bb.w;
        *reinterpret_cast<float4*>(out + (size_t)(tg + tl) * OD + j0) = r;
    }
}

// ---------------------------------------------------------------------------

extern "C" void kernel_launch(void* const* d_in, const int* in_sizes, int n_in,
                              void* d_out, int out_size, void* d_ws, size_t ws_size,
                              hipStream_t stream)
{
    const int*   word_inputs  = (const int*)  d_in[0];
    const int*   char_ids     = (const int*)  d_in[1];
    const int*   char_lengths = (const int*)  d_in[2];
    const float* word_table   = (const float*)d_in[3];
    const float* char_table   = (const float*)d_in[4];
    const float* Wg           = (const float*)d_in[5];
    const float* bg           = (const float*)d_in[6];
    const float* Wp           = (const float*)d_in[7];
    const float* bp           = (const float*)d_in[8];
    const float* W_out        = (const float*)d_in[9];
    const float* b_out        = (const float*)d_in[10];

    float* out       = (float*)d_out;
    float* char_repr = (float*)d_ws;   // 8192 * 128 f32 = 4 MB scratch

    scan_kernel<<<NTOK, 256, 0, stream>>>(char_ids, char_lengths, char_table,
                                          Wg, bg, Wp, bp, char_repr);
    out_gemm<<<NTOK / TPB2, 256, 0, stream>>>(word_inputs, word_table, char_repr,
                                              W_out, b_out, out);
}

// Round 2
// 1859.771 us; speedup vs baseline: 2.6674x; 2.6674x over previous
//
#include <hip/hip_runtime.h>
#include <hip/hip_bf16.h>

#define NTOK 8192
#define SCC  16
#define CD   128
#define WD   512
#define OD   1024
#define ED   640   // WD + CD
#define TW   4     // tokens per scan workgroup

typedef __attribute__((ext_vector_type(8))) short short8;
typedef __attribute__((ext_vector_type(4))) float f32x4;

__device__ __forceinline__ unsigned short f2bf(float f) {
    union { float f; unsigned u; } v; v.f = f;
    unsigned r = v.u + 0x7FFF + ((v.u >> 16) & 1);   // RNE
    return (unsigned short)(r >> 16);
}

// ---------------------------------------------------------------------------
// Kernel 0: pack Wg(384x256)+Wp(128x256) fp32 -> bf16 B-fragment layout.
// Fragment geometry for mfma_f32_16x16x32_bf16, B = K(32) x N(16):
//   lane l holds B[k=(l>>4)*8+e][n=l&15], e=0..7  (16 contiguous bytes).
// Feature n for (wave w, chunk c, lane): n = c*128 + w*16 + (l&15).
// Packed index: ((w*4+c)*8+kf)*64 + lane, each entry = uint4 (8 bf16).
// ---------------------------------------------------------------------------
__global__ __launch_bounds__(256) void pack_weights(
    const float* __restrict__ Wg, const float* __restrict__ Wp,
    uint4* __restrict__ packed)
{
    const int gid  = blockIdx.x * 256 + threadIdx.x;  // 0..16383
    const int lane = gid & 63;
    const int kf   = (gid >> 6) & 7;
    const int c    = (gid >> 9) & 3;
    const int w    = (gid >> 11) & 7;
    const int n    = c * 128 + w * 16 + (lane & 15);
    const int k0   = kf * 32 + (lane >> 4) * 8;
    const float* src = (n < 384) ? (Wg + n * 256 + k0) : (Wp + (n - 384) * 256 + k0);
    uint4 o;
    o.x = f2bf(src[0]) | ((unsigned)f2bf(src[1]) << 16);
    o.y = f2bf(src[2]) | ((unsigned)f2bf(src[3]) << 16);
    o.z = f2bf(src[4]) | ((unsigned)f2bf(src[5]) << 16);
    o.w = f2bf(src[6]) | ((unsigned)f2bf(src[7]) << 16);
    packed[gid] = o;
}

// ---------------------------------------------------------------------------
// Kernel 1: token-batched MFMA gated pyramid scan. 4 tokens/WG, 8 waves.
// Wave w owns output-feature d-slice [w*16, w*16+16) across all 4 chunks
// {g0,g1,g2,z} -> softmax+combine is lane-local, no gate LDS buffer.
// ---------------------------------------------------------------------------
__global__ __launch_bounds__(512, 4) void scan_mfma(
    const int*   __restrict__ char_ids,
    const int*   __restrict__ char_lengths,
    const float* __restrict__ char_table,
    const float* __restrict__ bg, const float* __restrict__ bp,
    const uint4* __restrict__ Wpacked,
    unsigned short* __restrict__ char_repr)
{
    __shared__ __align__(16) float S[TW * SCC * CD];          // 32 KB fp32 state
    __shared__ __align__(16) unsigned short X[64 * 256];      // 32 KB bf16, swizzled
    __shared__ int rowlist[64];
    __shared__ int Lsh[TW];

    const int wgt0 = blockIdx.x * TW;
    const int tid  = threadIdx.x;
    const int lane = tid & 63;
    const int w    = tid >> 6;         // wave 0..7
    const int col  = lane & 15;

    if (tid < TW) Lsh[tid] = char_lengths[wgt0 + tid];

    // init state: S[t][c][d] = char_table[ids[t][c]][d]   (float4 vectorized)
    for (int i = tid; i < TW * SCC * (CD / 4); i += 512) {
        const int t   = i >> 9;
        const int rem = i & 511;
        const int c   = rem >> 5;
        const int d4  = rem & 31;
        const int id  = char_ids[(wgt0 + t) * SCC + c];
        reinterpret_cast<float4*>(S)[i] =
            reinterpret_cast<const float4*>(char_table + id * CD)[d4];
    }

    // per-lane biases for the 4 chunks at feature d = w*16 + col
    const int dj = w * 16 + col;
    float biasv[4];
    biasv[0] = bg[dj];
    biasv[1] = bg[128 + dj];
    biasv[2] = bg[256 + dj];
    biasv[3] = bp[dj];

    __syncthreads();

    int L[TW];
#pragma unroll
    for (int t = 0; t < TW; ++t) L[t] = Lsh[t];
    const int maxL = max(max(L[0], L[1]), max(L[2], L[3]));

    for (int len = 1; len < maxL; ++len) {
        // active rows per token and packed offsets
        int A[TW], off[TW];
        int rows = 0;
#pragma unroll
        for (int t = 0; t < TW; ++t) { A[t] = max(L[t] - len, 0); off[t] = rows; rows += A[t]; }

        // row list (token<<8 | p) for the combine phase
        if (tid < 64 && tid < rows) {
            const int r = tid;
            const int t = (r >= off[1]) + (r >= off[2]) + (r >= off[3]);
            rowlist[r] = (t << 8) | (r - off[t]);
        }

        // build X: row r = [S[t][p] | S[t][p+1]] as bf16, XOR-swizzled
        for (int i = tid; i < rows * 128; i += 512) {
            const int r  = i >> 7;
            const int ku = i & 127;                       // u32 index in row
            const int t  = (r >= off[1]) + (r >= off[2]) + (r >= off[3]);
            const int p  = r - off[t];
            const float2 v = reinterpret_cast<const float2*>(S + t * 2048 + p * 128)[ku];
            const unsigned u = f2bf(v.x) | ((unsigned)f2bf(v.y) << 16);
            int baddr = (r << 9) + (ku << 2);
            baddr ^= (r & 7) << 4;
            *reinterpret_cast<unsigned*>(reinterpret_cast<char*>(X) + baddr) = u;
        }
        __syncthreads();

        const int mfrags = (rows + 15) >> 4;

        f32x4 acc[4][4];   // [m-frag][chunk]
#pragma unroll
        for (int m = 0; m < 4; ++m)
#pragma unroll
            for (int c = 0; c < 4; ++c) acc[m][c] = (f32x4){0.f, 0.f, 0.f, 0.f};

#pragma unroll
        for (int kf = 0; kf < 8; ++kf) {
            short8 b[4];
#pragma unroll
            for (int c = 0; c < 4; ++c) {
                const uint4 raw = Wpacked[((w * 4 + c) * 8 + kf) * 64 + lane];
                union { uint4 u; short8 s; } cv; cv.u = raw;
                b[c] = cv.s;
            }
#pragma unroll
            for (int m = 0; m < 4; ++m) {
                if (m < mfrags) {
                    const int row = m * 16 + col;
                    int baddr = (row << 9) + (kf << 6) + ((lane >> 4) << 4);
                    baddr ^= (row & 7) << 4;
                    const short8 a = *reinterpret_cast<const short8*>(
                        reinterpret_cast<const char*>(X) + baddr);
#pragma unroll
                    for (int c = 0; c < 4; ++c)
                        acc[m][c] = __builtin_amdgcn_mfma_f32_16x16x32_bf16(
                            a, b[c], acc[m][c], 0, 0, 0);
                }
            }
        }

        // combine: softmax over {g0,g1,g2} + convex mix, all lane-local.
        // D-frag: lane holds rows (lane>>4)*4+i, col = lane&15.
#pragma unroll
        for (int m = 0; m < 4; ++m) {
            if (m < mfrags) {
#pragma unroll
                for (int i = 0; i < 4; ++i) {
                    const int r = m * 16 + (lane >> 4) * 4 + i;
                    const int info = (r < rows) ? rowlist[r] : 0;
                    const int t = info >> 8, p = info & 255;
                    const float g0 = acc[m][0][i] + biasv[0];
                    const float g1 = acc[m][1][i] + biasv[1];
                    const float g2 = acc[m][2][i] + biasv[2];
                    const float z  = acc[m][3][i] + biasv[3];
                    const float mx = fmaxf(fmaxf(g0, g1), g2);
                    const float e0 = __expf(g0 - mx);
                    const float e1 = __expf(g1 - mx);
                    const float e2 = __expf(g2 - mx);
                    const float left  = S[t * 2048 + p * 128 + dj];
                    const float right = S[t * 2048 + (p + 1) * 128 + dj];
                    acc[m][0][i] = (e0 * left + e1 * right + e2 * z) / (e0 + e1 + e2);
                }
            }
        }
        __syncthreads();   // all S reads done before writes

#pragma unroll
        for (int m = 0; m < 4; ++m) {
            if (m < mfrags) {
#pragma unroll
                for (int i = 0; i < 4; ++i) {
                    const int r = m * 16 + (lane >> 4) * 4 + i;
                    if (r < rows) {
                        const int info = rowlist[r];
                        const int t = info >> 8, p = info & 255;
                        S[t * 2048 + p * 128 + dj] = acc[m][0][i];
                    }
                }
            }
        }
        __syncthreads();
    }

    // char representation = S[t][0][:], stored bf16
    for (int i = tid; i < TW * CD; i += 512) {
        const int t = i >> 7, d = i & 127;
        char_repr[(wgt0 + t) * CD + d] = f2bf(S[t * 2048 + d]);
    }
}

// ---------------------------------------------------------------------------
// Kernel 2: out[t][j] = b_out[j] + emb[t] . W_out[j]
// ---------------------------------------------------------------------------
#define TPB2 8

__global__ __launch_bounds__(256) void out_gemm(
    const int*   __restrict__ word_inputs,
    const float* __restrict__ word_table,
    const unsigned short* __restrict__ char_repr,   // bf16 bits
    const float* __restrict__ W_out,
    const float* __restrict__ b_out,
    float*       __restrict__ out)
{
    __shared__ __align__(16) float E[TPB2 * ED];  // 20 KB

    const int tg  = blockIdx.x * TPB2;
    const int tid = threadIdx.x;

    for (int i = tid; i < TPB2 * WD; i += 256) {
        const int tl = i >> 9, k = i & 511;
        E[tl * ED + k] = word_table[(size_t)word_inputs[tg + tl] * WD + k];
    }
    for (int i = tid; i < TPB2 * CD; i += 256) {
        const int tl = i >> 7, k = i & 127;
        union { unsigned u; float f; } q;
        q.u = ((unsigned)char_repr[(tg + tl) * CD + k]) << 16;
        E[tl * ED + WD + k] = q.f;
    }
    __syncthreads();

    const int j0 = tid * 4;
    float acc[TPB2][4];
#pragma unroll
    for (int tl = 0; tl < TPB2; ++tl)
#pragma unroll
        for (int jj = 0; jj < 4; ++jj) acc[tl][jj] = 0.f;

#pragma unroll 2
    for (int kc = 0; kc < ED / 4; ++kc) {
        const int k = kc * 4;
        float4 wr[4];
#pragma unroll
        for (int jj = 0; jj < 4; ++jj)
            wr[jj] = *reinterpret_cast<const float4*>(W_out + (size_t)(j0 + jj) * ED + k);
#pragma unroll
        for (int tl = 0; tl < TPB2; ++tl) {
            const float4 e = *reinterpret_cast<const float4*>(E + tl * ED + k);
#pragma unroll
            for (int jj = 0; jj < 4; ++jj) {
                acc[tl][jj] = fmaf(wr[jj].x, e.x, acc[tl][jj]);
                acc[tl][jj] = fmaf(wr[jj].y, e.y, acc[tl][jj]);
                acc[tl][jj] = fmaf(wr[jj].z, e.z, acc[tl][jj]);
                acc[tl][jj] = fmaf(wr[jj].w, e.w, acc[tl][jj]);
            }
        }
    }

    const float4 bb = *reinterpret_cast<const float4*>(b_out + j0);
#pragma unroll
    for (int tl = 0; tl < TPB2; ++tl) {
        float4 r;
        r.x = acc[tl][0] + bb.x;
        r.y = acc[tl][1] + bb.y;
        r.z = acc[tl][2] + bb.z;
        r.w = acc[tl][3] + bb.w;
        *reinterpret_cast<float4*>(out + (size_t)(tg + tl) * OD + j0) = r;
    }
}

// ---------------------------------------------------------------------------

extern "C" void kernel_launch(void* const* d_in, const int* in_sizes, int n_in,
                              void* d_out, int out_size, void* d_ws, size_t ws_size,
                              hipStream_t stream)
{
    const int*   word_inputs  = (const int*)  d_in[0];
    const int*   char_ids     = (const int*)  d_in[1];
    const int*   char_lengths = (const int*)  d_in[2];
    const float* word_table   = (const float*)d_in[3];
    const float* char_table   = (const float*)d_in[4];
    const float* Wg           = (const float*)d_in[5];
    const float* bg           = (const float*)d_in[6];
    const float* Wp           = (const float*)d_in[7];
    const float* bp           = (const float*)d_in[8];
    const float* W_out        = (const float*)d_in[9];
    const float* b_out        = (const float*)d_in[10];

    float* out = (float*)d_out;
    unsigned short* char_repr = (unsigned short*)d_ws;              // 2 MB bf16
    uint4* Wpacked = (uint4*)((char*)d_ws + 2 * 1024 * 1024);       // 256 KB

    pack_weights<<<64, 256, 0, stream>>>(Wg, Wp, Wpacked);
    scan_mfma<<<NTOK / TW, 512, 0, stream>>>(char_ids, char_lengths, char_table,
                                             bg, bp, Wpacked, char_repr);
    out_gemm<<<NTOK / TPB2, 256, 0, stream>>>(word_inputs, word_table, char_repr,
                                              W_out, b_out, out);
}

// Round 4
// 620.798 us; speedup vs baseline: 7.9908x; 2.9958x over previous
//
#include <hip/hip_runtime.h>
#include <hip/hip_bf16.h>

#define NTOK 8192
#define SCC  16
#define CD   128
#define WD   512
#define OD   1024
#define ED   640   // WD + CD
#define TW   4     // tokens per scan workgroup

typedef __attribute__((ext_vector_type(8))) short short8;
typedef __attribute__((ext_vector_type(4))) float f32x4;

__device__ __forceinline__ unsigned short f2bf(float f) {
    union { float f; unsigned u; } v; v.f = f;
    unsigned r = v.u + 0x7FFF + ((v.u >> 16) & 1);   // RNE
    return (unsigned short)(r >> 16);
}

// ---------------------------------------------------------------------------
// Deterministic stable counting sort of tokens by length (16 bins).
// hist via integer atomics (result exact & order-independent), prefix on one
// thread, then a fully deterministic stable scatter: one block per bin scans
// all tokens in chunks with an LDS prefix-sum. Same `order` bits every call.
// ws ints: [0..15]=hist [16..31]=base [32..47]=unused [48..48+NTOK)=order
// ---------------------------------------------------------------------------
__global__ void sort_zero(int* s) { if (threadIdx.x < 48) s[threadIdx.x] = 0; }

__global__ void sort_hist(const int* __restrict__ lengths, int* __restrict__ s) {
    const int i = blockIdx.x * 256 + threadIdx.x;
    if (i < NTOK) atomicAdd(&s[lengths[i] - 1], 1);
}

__global__ void sort_prefix(int* s) {
    if (threadIdx.x == 0) {
        int acc = 0;
        for (int b = 0; b < 16; ++b) { s[16 + b] = acc; acc += s[b]; }
    }
}

__global__ __launch_bounds__(256) void sort_scatter_det(
    const int* __restrict__ lengths, int* __restrict__ s)
{
    __shared__ int sc[256];
    __shared__ int running;
    const int b   = blockIdx.x;      // bin = length-1
    const int tid = threadIdx.x;
    if (tid == 0) running = s[16 + b];
    __syncthreads();
    for (int c0 = 0; c0 < NTOK; c0 += 256) {
        const int i = c0 + tid;
        const int f = (lengths[i] - 1 == b) ? 1 : 0;
        sc[tid] = f;
        __syncthreads();
        // Hillis-Steele inclusive scan over 256 flags
        for (int offs = 1; offs < 256; offs <<= 1) {
            const int v = (tid >= offs) ? sc[tid - offs] : 0;
            __syncthreads();
            sc[tid] += v;
            __syncthreads();
        }
        if (f) s[48 + running + sc[tid] - 1] = i;
        const int tot = sc[255];
        __syncthreads();
        if (tid == 0) running += tot;
        __syncthreads();
    }
}

// ---------------------------------------------------------------------------
// Kernel 0: pack Wg(384x256)+Wp(128x256) fp32 -> bf16 B-fragment layout.
// lane l holds B[k=(l>>4)*8+e][n=l&15], e=0..7. n = c*128 + w*16 + (l&15).
// index: ((w*4+c)*8+kf)*64 + lane, entry = uint4 (8 bf16 along k).
// ---------------------------------------------------------------------------
__global__ __launch_bounds__(256) void pack_weights(
    const float* __restrict__ Wg, const float* __restrict__ Wp,
    uint4* __restrict__ packed)
{
    const int gid  = blockIdx.x * 256 + threadIdx.x;  // 0..16383
    const int lane = gid & 63;
    const int kf   = (gid >> 6) & 7;
    const int c    = (gid >> 9) & 3;
    const int w    = (gid >> 11) & 7;
    const int n    = c * 128 + w * 16 + (lane & 15);
    const int k0   = kf * 32 + (lane >> 4) * 8;
    const float* src = (n < 384) ? (Wg + n * 256 + k0) : (Wp + (n - 384) * 256 + k0);
    uint4 o;
    o.x = f2bf(src[0]) | ((unsigned)f2bf(src[1]) << 16);
    o.y = f2bf(src[2]) | ((unsigned)f2bf(src[3]) << 16);
    o.z = f2bf(src[4]) | ((unsigned)f2bf(src[5]) << 16);
    o.w = f2bf(src[6]) | ((unsigned)f2bf(src[7]) << 16);
    packed[gid] = o;
}

// ---------------------------------------------------------------------------
// Kernel 1: token-batched MFMA gated pyramid scan. 4 (length-sorted) tokens
// per WG, 8 waves. Wave w owns feature slice [w*16,w*16+16) over all 4 chunks
// {g0,g1,g2,z} -> softmax+combine lane-local.
// ---------------------------------------------------------------------------
__global__ __launch_bounds__(512, 2) void scan_mfma(
    const int*   __restrict__ char_ids,
    const int*   __restrict__ char_lengths,
    const float* __restrict__ char_table,
    const float* __restrict__ bg, const float* __restrict__ bp,
    const uint4* __restrict__ Wpacked,
    const int*   __restrict__ order,
    unsigned short* __restrict__ char_repr)
{
    __shared__ __align__(16) float S[TW * SCC * CD];          // 32 KB fp32 state
    __shared__ __align__(16) unsigned short X[64 * 256];      // 32 KB bf16, swizzled
    __shared__ int rowlist[64];
    __shared__ int toksh[TW];
    __shared__ int Lsh[TW];

    const int tid  = threadIdx.x;
    const int lane = tid & 63;
    const int w    = tid >> 6;         // wave 0..7
    const int col  = lane & 15;

    if (tid < TW) {
        const int tok = order[blockIdx.x * TW + tid];
        toksh[tid] = tok;
        Lsh[tid]   = char_lengths[tok];
    }
    __syncthreads();

    // init state: S[t][c][d] = char_table[ids[tok[t]][c]][d]
    for (int i = tid; i < TW * SCC * (CD / 4); i += 512) {
        const int t   = i >> 9;
        const int rem = i & 511;
        const int c   = rem >> 5;
        const int d4  = rem & 31;
        const int id  = char_ids[toksh[t] * SCC + c];
        reinterpret_cast<float4*>(S)[i] =
            reinterpret_cast<const float4*>(char_table + id * CD)[d4];
    }

    // per-lane biases for the 4 chunks at feature d = w*16 + col
    const int dj = w * 16 + col;
    float biasv[4];
    biasv[0] = bg[dj];
    biasv[1] = bg[128 + dj];
    biasv[2] = bg[256 + dj];
    biasv[3] = bp[dj];

    int L[TW];
#pragma unroll
    for (int t = 0; t < TW; ++t) L[t] = Lsh[t];
    const int maxL = max(max(L[0], L[1]), max(L[2], L[3]));

    __syncthreads();

    for (int len = 1; len < maxL; ++len) {
        int A[TW], off[TW];
        int rows = 0;
#pragma unroll
        for (int t = 0; t < TW; ++t) { A[t] = max(L[t] - len, 0); off[t] = rows; rows += A[t]; }

        if (tid < 64 && tid < rows) {
            const int r = tid;
            const int t = (r >= off[1]) + (r >= off[2]) + (r >= off[3]);
            rowlist[r] = (t << 8) | (r - off[t]);
        }

        // build X: row r = [S[t][p] | S[t][p+1]] bf16, XOR-swizzled
        for (int i = tid; i < rows * 128; i += 512) {
            const int r  = i >> 7;
            const int ku = i & 127;
            const int t  = (r >= off[1]) + (r >= off[2]) + (r >= off[3]);
            const int p  = r - off[t];
            const float2 v = reinterpret_cast<const float2*>(S + t * 2048 + p * 128)[ku];
            const unsigned u = f2bf(v.x) | ((unsigned)f2bf(v.y) << 16);
            int baddr = (r << 9) + (ku << 2);
            baddr ^= (r & 7) << 4;
            *reinterpret_cast<unsigned*>(reinterpret_cast<char*>(X) + baddr) = u;
        }
        __syncthreads();

        const int mfrags = (rows + 15) >> 4;

        f32x4 acc[4][4];   // [m-frag][chunk]
#pragma unroll
        for (int m = 0; m < 4; ++m)
#pragma unroll
            for (int c = 0; c < 4; ++c) acc[m][c] = (f32x4){0.f, 0.f, 0.f, 0.f};

#pragma unroll
        for (int kf = 0; kf < 8; ++kf) {
            short8 a[4];
#pragma unroll
            for (int m = 0; m < 4; ++m) {
                if (m < mfrags) {
                    const int row = m * 16 + col;
                    int baddr = (row << 9) + (kf << 6) + ((lane >> 4) << 4);
                    baddr ^= (row & 7) << 4;
                    a[m] = *reinterpret_cast<const short8*>(
                        reinterpret_cast<const char*>(X) + baddr);
                }
            }
#pragma unroll
            for (int c = 0; c < 4; ++c) {
                const uint4 raw = Wpacked[((w * 4 + c) * 8 + kf) * 64 + lane];
                union { uint4 u; short8 s; } cv; cv.u = raw;
#pragma unroll
                for (int m = 0; m < 4; ++m) {
                    if (m < mfrags)
                        acc[m][c] = __builtin_amdgcn_mfma_f32_16x16x32_bf16(
                            a[m], cv.s, acc[m][c], 0, 0, 0);
                }
            }
        }

        // combine: lane-local softmax over {g0,g1,g2} + convex mix
#pragma unroll
        for (int m = 0; m < 4; ++m) {
            if (m < mfrags) {
#pragma unroll
                for (int i = 0; i < 4; ++i) {
                    const int r = m * 16 + (lane >> 4) * 4 + i;
                    const int info = (r < rows) ? rowlist[r] : 0;
                    const int t = info >> 8, p = info & 255;
                    const float g0 = acc[m][0][i] + biasv[0];
                    const float g1 = acc[m][1][i] + biasv[1];
                    const float g2 = acc[m][2][i] + biasv[2];
                    const float z  = acc[m][3][i] + biasv[3];
                    const float mx = fmaxf(fmaxf(g0, g1), g2);
                    const float e0 = __expf(g0 - mx);
                    const float e1 = __expf(g1 - mx);
                    const float e2 = __expf(g2 - mx);
                    const float left  = S[t * 2048 + p * 128 + dj];
                    const float right = S[t * 2048 + (p + 1) * 128 + dj];
                    acc[m][0][i] = (e0 * left + e1 * right + e2 * z) / (e0 + e1 + e2);
                }
            }
        }
        __syncthreads();   // all S reads done before writes

#pragma unroll
        for (int m = 0; m < 4; ++m) {
            if (m < mfrags) {
#pragma unroll
                for (int i = 0; i < 4; ++i) {
                    const int r = m * 16 + (lane >> 4) * 4 + i;
                    if (r < rows) {
                        const int info = rowlist[r];
                        const int t = info >> 8, p = info & 255;
                        S[t * 2048 + p * 128 + dj] = acc[m][0][i];
                    }
                }
            }
        }
        __syncthreads();
    }

    // char representation = S[t][0][:], stored bf16
    for (int i = tid; i < TW * CD; i += 512) {
        const int t = i >> 7, d = i & 127;
        char_repr[toksh[t] * CD + d] = f2bf(S[t * 2048 + d]);
    }
}

// ---------------------------------------------------------------------------
// Kernel 2: out[t][j] = b_out[j] + emb[t] . W_out[j]
// ---------------------------------------------------------------------------
#define TPB2 16

__global__ __launch_bounds__(256) void out_gemm(
    const int*   __restrict__ word_inputs,
    const float* __restrict__ word_table,
    const unsigned short* __restrict__ char_repr,   // bf16 bits
    const float* __restrict__ W_out,
    const float* __restrict__ b_out,
    float*       __restrict__ out)
{
    __shared__ __align__(16) float E[TPB2 * ED];  // 40 KB

    const int tg  = blockIdx.x * TPB2;
    const int tid = threadIdx.x;

    for (int i = tid; i < TPB2 * WD; i += 256) {
        const int tl = i >> 9, k = i & 511;
        E[tl * ED + k] = word_table[(size_t)word_inputs[tg + tl] * WD + k];
    }
    for (int i = tid; i < TPB2 * CD; i += 256) {
        const int tl = i >> 7, k = i & 127;
        union { unsigned u; float f; } q;
        q.u = ((unsigned)char_repr[(tg + tl) * CD + k]) << 16;
        E[tl * ED + WD + k] = q.f;
    }
    __syncthreads();

    const int j0 = tid * 4;
    float acc[TPB2][4];
#pragma unroll
    for (int tl = 0; tl < TPB2; ++tl)
#pragma unroll
        for (int jj = 0; jj < 4; ++jj) acc[tl][jj] = 0.f;

#pragma unroll 2
    for (int kc = 0; kc < ED / 4; ++kc) {
        const int k = kc * 4;
        float4 wr[4];
#pragma unroll
        for (int jj = 0; jj < 4; ++jj)
            wr[jj] = *reinterpret_cast<const float4*>(W_out + (size_t)(j0 + jj) * ED + k);
#pragma unroll
        for (int tl = 0; tl < TPB2; ++tl) {
            const float4 e = *reinterpret_cast<const float4*>(E + tl * ED + k);
#pragma unroll
            for (int jj = 0; jj < 4; ++jj) {
                acc[tl][jj] = fmaf(wr[jj].x, e.x, acc[tl][jj]);
                acc[tl][jj] = fmaf(wr[jj].y, e.y, acc[tl][jj]);
                acc[tl][jj] = fmaf(wr[jj].z, e.z, acc[tl][jj]);
                acc[tl][jj] = fmaf(wr[jj].w, e.w, acc[tl][jj]);
            }
        }
    }

    const float4 bb = *reinterpret_cast<const float4*>(b_out + j0);
#pragma unroll
    for (int tl = 0; tl < TPB2; ++tl) {
        float4 r;
        r.x = acc[tl][0] + bb.x;
        r.y = acc[tl][1] + bb.y;
        r.z = acc[tl][2] + bb.z;
        r.w = acc[tl][3] + bb.w;
        *reinterpret_cast<float4*>(out + (size_t)(tg + tl) * OD + j0) = r;
    }
}

// ---------------------------------------------------------------------------

extern "C" void kernel_launch(void* const* d_in, const int* in_sizes, int n_in,
                              void* d_out, int out_size, void* d_ws, size_t ws_size,
                              hipStream_t stream)
{
    const int*   word_inputs  = (const int*)  d_in[0];
    const int*   char_ids     = (const int*)  d_in[1];
    const int*   char_lengths = (const int*)  d_in[2];
    const float* word_table   = (const float*)d_in[3];
    const float* char_table   = (const float*)d_in[4];
    const float* Wg           = (const float*)d_in[5];
    const float* bg           = (const float*)d_in[6];
    const float* Wp           = (const float*)d_in[7];
    const float* bp           = (const float*)d_in[8];
    const float* W_out        = (const float*)d_in[9];
    const float* b_out        = (const float*)d_in[10];

    float* out = (float*)d_out;
    unsigned short* char_repr = (unsigned short*)d_ws;              // 2 MB bf16
    uint4* Wpacked = (uint4*)((char*)d_ws + 2 * 1024 * 1024);       // 256 KB
    int*   sortbuf = (int*)((char*)d_ws + 2 * 1024 * 1024 + 256 * 1024);
    const int* order = sortbuf + 48;

    pack_weights<<<64, 256, 0, stream>>>(Wg, Wp, Wpacked);
    sort_zero<<<1, 64, 0, stream>>>(sortbuf);
    sort_hist<<<NTOK / 256, 256, 0, stream>>>(char_lengths, sortbuf);
    sort_prefix<<<1, 64, 0, stream>>>(sortbuf);
    sort_scatter_det<<<16, 256, 0, stream>>>(char_lengths, sortbuf);

    scan_mfma<<<NTOK / TW, 512, 0, stream>>>(char_ids, char_lengths, char_table,
                                             bg, bp, Wpacked, order, char_repr);
    out_gemm<<<NTOK / TPB2, 256, 0, stream>>>(word_inputs, word_table, char_repr,
                                              W_out, b_out, out);
}

// Round 5
// 606.376 us; speedup vs baseline: 8.1809x; 1.0238x over previous
//
#include <hip/hip_runtime.h>
#include <hip/hip_bf16.h>

#define NTOK 8192
#define SCC  16
#define CD   128
#define WD   512
#define OD   1024
#define ED   640   // WD + CD
#define TW   4     // tokens per scan workgroup

typedef __attribute__((ext_vector_type(8))) short short8;
typedef __attribute__((ext_vector_type(4))) float f32x4;

__device__ __forceinline__ unsigned short f2bf(float f) {
    union { float f; unsigned u; } v; v.f = f;
    unsigned r = v.u + 0x7FFF + ((v.u >> 16) & 1);   // RNE
    return (unsigned short)(r >> 16);
}

// ---------------------------------------------------------------------------
// Deterministic stable counting sort of tokens by length (16 bins).
// ws ints: [0..15]=hist [16..31]=base [32..47]=unused [48..48+NTOK)=order
// ---------------------------------------------------------------------------
__global__ void sort_zero(int* s) { if (threadIdx.x < 48) s[threadIdx.x] = 0; }

__global__ void sort_hist(const int* __restrict__ lengths, int* __restrict__ s) {
    const int i = blockIdx.x * 256 + threadIdx.x;
    if (i < NTOK) atomicAdd(&s[lengths[i] - 1], 1);
}

__global__ void sort_prefix(int* s) {
    if (threadIdx.x == 0) {
        int acc = 0;
        for (int b = 0; b < 16; ++b) { s[16 + b] = acc; acc += s[b]; }
    }
}

// one block per bin; ballot-based stable rank — bit-deterministic every call
__global__ __launch_bounds__(256) void sort_scatter_det(
    const int* __restrict__ lengths, int* __restrict__ s)
{
    __shared__ int wsum[4];
    __shared__ int running;
    const int b   = blockIdx.x;
    const int tid = threadIdx.x;
    if (tid == 0) running = s[16 + b];
    __syncthreads();
    for (int c0 = 0; c0 < NTOK; c0 += 256) {
        const int i = c0 + tid;
        const bool f = (lengths[i] - 1 == b);
        const unsigned long long m = __ballot(f);
        const int wv = tid >> 6;
        if ((tid & 63) == 0) wsum[wv] = __popcll(m);
        __syncthreads();
        int excl = 0;
#pragma unroll
        for (int k = 0; k < 4; ++k) if (k < wv) excl += wsum[k];
        const int lanerank = __popcll(m & ((1ull << (tid & 63)) - 1ull));
        if (f) s[48 + running + excl + lanerank] = i;
        const int tot = wsum[0] + wsum[1] + wsum[2] + wsum[3];
        __syncthreads();
        if (tid == 0) running += tot;
        __syncthreads();
    }
}

// ---------------------------------------------------------------------------
// Kernel 0: pack Wg(384x256)+Wp(128x256) fp32 -> bf16 B-fragment layout.
// lane l holds B[k=(l>>4)*8+e][n=l&15], e=0..7. n = c*128 + w*16 + (l&15).
// index: ((w*4+c)*8+kf)*64 + lane, entry = uint4 (8 bf16 along k).
// ---------------------------------------------------------------------------
__global__ __launch_bounds__(256) void pack_weights(
    const float* __restrict__ Wg, const float* __restrict__ Wp,
    uint4* __restrict__ packed)
{
    const int gid  = blockIdx.x * 256 + threadIdx.x;  // 0..16383
    const int lane = gid & 63;
    const int kf   = (gid >> 6) & 7;
    const int c    = (gid >> 9) & 3;
    const int w    = (gid >> 11) & 7;
    const int n    = c * 128 + w * 16 + (lane & 15);
    const int k0   = kf * 32 + (lane >> 4) * 8;
    const float* src = (n < 384) ? (Wg + n * 256 + k0) : (Wp + (n - 384) * 256 + k0);
    uint4 o;
    o.x = f2bf(src[0]) | ((unsigned)f2bf(src[1]) << 16);
    o.y = f2bf(src[2]) | ((unsigned)f2bf(src[3]) << 16);
    o.z = f2bf(src[4]) | ((unsigned)f2bf(src[5]) << 16);
    o.w = f2bf(src[6]) | ((unsigned)f2bf(src[7]) << 16);
    packed[gid] = o;
}

// ---------------------------------------------------------------------------
// Kernel 1: MFMA gated pyramid scan, weights register-resident.
// 4 sorted tokens/WG, 8 waves. X row r = p*4 + t (static across steps):
// D-frag element i IS token i; p = m*4 + (lane>>4). Combine writes bf16
// results straight into X (left @ row p, right @ row p-1) + masked fp32 S.
// ---------------------------------------------------------------------------
__global__ __launch_bounds__(512, 2) void scan_mfma(
    const int*   __restrict__ char_ids,
    const int*   __restrict__ char_lengths,
    const float* __restrict__ char_table,
    const float* __restrict__ bg, const float* __restrict__ bp,
    const uint4* __restrict__ Wpacked,
    const int*   __restrict__ order,
    unsigned short* __restrict__ char_repr)
{
    __shared__ __align__(16) float S[TW * SCC * CD];          // 32 KB fp32 state
    __shared__ __align__(16) unsigned short X[64 * 256];      // 32 KB bf16, swizzled
    __shared__ int toksh[TW];
    __shared__ int Lsh[TW];

    const int tid  = threadIdx.x;
    const int lane = tid & 63;
    const int w    = tid >> 6;         // wave 0..7
    const int col  = lane & 15;
    const int q    = lane >> 4;        // 0..3

    if (tid < TW) {
        const int tok = order[blockIdx.x * TW + tid];
        toksh[tid] = tok;
        Lsh[tid]   = char_lengths[tok];
    }

    // ---- weights into registers: wave w's slice, 128 VGPRs, static idx ----
    short8 wreg[4][8];
#pragma unroll
    for (int c = 0; c < 4; ++c)
#pragma unroll
        for (int kf = 0; kf < 8; ++kf) {
            union { uint4 u; short8 s; } cv;
            cv.u = Wpacked[((w * 4 + c) * 8 + kf) * 64 + lane];
            wreg[c][kf] = cv.s;
        }

    const int dj = w * 16 + col;
    float biasv[4];
    biasv[0] = bg[dj];
    biasv[1] = bg[128 + dj];
    biasv[2] = bg[256 + dj];
    biasv[3] = bp[dj];

    __syncthreads();

    // init state: S[t][c][d] = char_table[ids[tok[t]][c]][d]
    for (int i = tid; i < TW * SCC * (CD / 4); i += 512) {
        const int t   = i >> 9;
        const int rem = i & 511;
        const int c   = rem >> 5;
        const int d4  = rem & 31;
        const int id  = char_ids[toksh[t] * SCC + c];
        reinterpret_cast<float4*>(S)[i] =
            reinterpret_cast<const float4*>(char_table + id * CD)[d4];
    }

    int L[TW];
#pragma unroll
    for (int t = 0; t < TW; ++t) L[t] = Lsh[t];
    const int maxL = max(max(L[0], L[1]), max(L[2], L[3]));

    __syncthreads();

    // init X once: row r=p*4+t = [S[t][p] | S[t][p+1]] bf16 (contiguous 256f),
    // rows with p=15 zero-filled (never valid, keeps MFMA inputs finite).
    for (int i = tid; i < 64 * 128; i += 512) {
        const int r  = i >> 7;
        const int ku = i & 127;
        const int p  = r >> 2;
        const int t  = r & 3;
        unsigned u = 0u;
        if (p < 15) {
            const float2 v = reinterpret_cast<const float2*>(S + t * 2048 + p * 128)[ku];
            u = f2bf(v.x) | ((unsigned)f2bf(v.y) << 16);
        }
        int baddr = (r << 9) + (ku << 2);
        baddr ^= (r & 7) << 4;
        *reinterpret_cast<unsigned*>(reinterpret_cast<char*>(X) + baddr) = u;
    }
    __syncthreads();

    for (int len = 1; len < maxL; ++len) {
        const int Amax   = maxL - len;
        const int mfrags = (4 * Amax + 15) >> 4;

        f32x4 acc[4][4];   // [m-frag][chunk]
#pragma unroll
        for (int m = 0; m < 4; ++m)
#pragma unroll
            for (int c = 0; c < 4; ++c) acc[m][c] = (f32x4){0.f, 0.f, 0.f, 0.f};

        // ---- MFMA phase: A from LDS X, B from registers ----
#pragma unroll
        for (int kf = 0; kf < 8; ++kf) {
            short8 a[4];
#pragma unroll
            for (int m = 0; m < 4; ++m) {
                if (m < mfrags) {
                    const int row = m * 16 + col;
                    int baddr = (row << 9) + (kf << 6) + (q << 4);
                    baddr ^= (row & 7) << 4;
                    a[m] = *reinterpret_cast<const short8*>(
                        reinterpret_cast<const char*>(X) + baddr);
                }
            }
#pragma unroll
            for (int c = 0; c < 4; ++c) {
#pragma unroll
                for (int m = 0; m < 4; ++m) {
                    if (m < mfrags)
                        acc[m][c] = __builtin_amdgcn_mfma_f32_16x16x32_bf16(
                            a[m], wreg[c][kf], acc[m][c], 0, 0, 0);
                }
            }
        }

        // ---- combine: lane-local softmax + convex mix. t = i, p = m*4+q ----
#pragma unroll
        for (int m = 0; m < 4; ++m) {
            if (m < mfrags) {
                const int p = m * 4 + q;
#pragma unroll
                for (int i = 0; i < 4; ++i) {
                    const float g0 = acc[m][0][i] + biasv[0];
                    const float g1 = acc[m][1][i] + biasv[1];
                    const float g2 = acc[m][2][i] + biasv[2];
                    const float z  = acc[m][3][i] + biasv[3];
                    const float mx = fmaxf(fmaxf(g0, g1), g2);
                    const float e0 = __expf(g0 - mx);
                    const float e1 = __expf(g1 - mx);
                    const float e2 = __expf(g2 - mx);
                    const float left  = S[i * 2048 + p * 128 + dj];
                    const float right = S[i * 2048 + (p + 1) * 128 + dj];
                    acc[m][0][i] = (e0 * left + e1 * right + e2 * z) / (e0 + e1 + e2);
                }
            }
        }
        __syncthreads();   // all X-reads (MFMA) and S-reads (combine) done

        // ---- write phase: masked fp32 S + bf16 X (left @ p, right @ p-1) ----
#pragma unroll
        for (int m = 0; m < 4; ++m) {
            if (m < mfrags) {
                const int p = m * 4 + q;
#pragma unroll
                for (int i = 0; i < 4; ++i) {
                    const float val = acc[m][0][i];
                    if (p < L[i] - len) S[i * 2048 + p * 128 + dj] = val;
                    const unsigned short bv = f2bf(val);
                    const int rl = m * 16 + q * 4 + i;          // row p*4+i
                    int bl = (rl << 9) + (dj << 1);
                    bl ^= (rl & 7) << 4;
                    *reinterpret_cast<unsigned short*>(
                        reinterpret_cast<char*>(X) + bl) = bv;
                    if (p >= 1) {
                        const int rr = rl - 4;                  // row (p-1)*4+i
                        int br = (rr << 9) + 256 + (dj << 1);
                        br ^= (rr & 7) << 4;
                        *reinterpret_cast<unsigned short*>(
                            reinterpret_cast<char*>(X) + br) = bv;
                    }
                }
            }
        }
        __syncthreads();
    }

    // char representation = S[t][0][:], stored bf16
    for (int i = tid; i < TW * CD; i += 512) {
        const int t = i >> 7, d = i & 127;
        char_repr[toksh[t] * CD + d] = f2bf(S[t * 2048 + d]);
    }
}

// ---------------------------------------------------------------------------
// Kernel 2: out[t][j] = b_out[j] + emb[t] . W_out[j]
// ---------------------------------------------------------------------------
#define TPB2 16

__global__ __launch_bounds__(256) void out_gemm(
    const int*   __restrict__ word_inputs,
    const float* __restrict__ word_table,
    const unsigned short* __restrict__ char_repr,   // bf16 bits
    const float* __restrict__ W_out,
    const float* __restrict__ b_out,
    float*       __restrict__ out)
{
    __shared__ __align__(16) float E[TPB2 * ED];  // 40 KB

    const int tg  = blockIdx.x * TPB2;
    const int tid = threadIdx.x;

    for (int i = tid; i < TPB2 * WD; i += 256) {
        const int tl = i >> 9, k = i & 511;
        E[tl * ED + k] = word_table[(size_t)word_inputs[tg + tl] * WD + k];
    }
    for (int i = tid; i < TPB2 * CD; i += 256) {
        const int tl = i >> 7, k = i & 127;
        union { unsigned u; float f; } qq;
        qq.u = ((unsigned)char_repr[(tg + tl) * CD + k]) << 16;
        E[tl * ED + WD + k] = qq.f;
    }
    __syncthreads();

    const int j0 = tid * 4;
    float acc[TPB2][4];
#pragma unroll
    for (int tl = 0; tl < TPB2; ++tl)
#pragma unroll
        for (int jj = 0; jj < 4; ++jj) acc[tl][jj] = 0.f;

#pragma unroll 2
    for (int kc = 0; kc < ED / 4; ++kc) {
        const int k = kc * 4;
        float4 wr[4];
#pragma unroll
        for (int jj = 0; jj < 4; ++jj)
            wr[jj] = *reinterpret_cast<const float4*>(W_out + (size_t)(j0 + jj) * ED + k);
#pragma unroll
        for (int tl = 0; tl < TPB2; ++tl) {
            const float4 e = *reinterpret_cast<const float4*>(E + tl * ED + k);
#pragma unroll
            for (int jj = 0; jj < 4; ++jj) {
                acc[tl][jj] = fmaf(wr[jj].x, e.x, acc[tl][jj]);
                acc[tl][jj] = fmaf(wr[jj].y, e.y, acc[tl][jj]);
                acc[tl][jj] = fmaf(wr[jj].z, e.z, acc[tl][jj]);
                acc[tl][jj] = fmaf(wr[jj].w, e.w, acc[tl][jj]);
            }
        }
    }

    const float4 bb = *reinterpret_cast<const float4*>(b_out + j0);
#pragma unroll
    for (int tl = 0; tl < TPB2; ++tl) {
        float4 r;
        r.x = acc[tl][0] + bb.x;
        r.y = acc[tl][1] + bb.y;
        r.z = acc[tl][2] + bb.z;
        r.w = acc[tl][3] + bb.w;
        *reinterpret_cast<float4*>(out + (size_t)(tg + tl) * OD + j0) = r;
    }
}

// ---------------------------------------------------------------------------

extern "C" void kernel_launch(void* const* d_in, const int* in_sizes, int n_in,
                              void* d_out, int out_size, void* d_ws, size_t ws_size,
                              hipStream_t stream)
{
    const int*   word_inputs  = (const int*)  d_in[0];
    const int*   char_ids     = (const int*)  d_in[1];
    const int*   char_lengths = (const int*)  d_in[2];
    const float* word_table   = (const float*)d_in[3];
    const float* char_table   = (const float*)d_in[4];
    const float* Wg           = (const float*)d_in[5];
    const float* bg           = (const float*)d_in[6];
    const float* Wp           = (const float*)d_in[7];
    const float* bp           = (const float*)d_in[8];
    const float* W_out        = (const float*)d_in[9];
    const float* b_out        = (const float*)d_in[10];

    float* out = (float*)d_out;
    unsigned short* char_repr = (unsigned short*)d_ws;              // 2 MB bf16
    uint4* Wpacked = (uint4*)((char*)d_ws + 2 * 1024 * 1024);       // 256 KB
    int*   sortbuf = (int*)((char*)d_ws + 2 * 1024 * 1024 + 256 * 1024);
    const int* order = sortbuf + 48;

    pack_weights<<<64, 256, 0, stream>>>(Wg, Wp, Wpacked);
    sort_zero<<<1, 64, 0, stream>>>(sortbuf);
    sort_hist<<<NTOK / 256, 256, 0, stream>>>(char_lengths, sortbuf);
    sort_prefix<<<1, 64, 0, stream>>>(sortbuf);
    sort_scatter_det<<<16, 256, 0, stream>>>(char_lengths, sortbuf);

    scan_mfma<<<NTOK / TW, 512, 0, stream>>>(char_ids, char_lengths, char_table,
                                             bg, bp, Wpacked, order, char_repr);
    out_gemm<<<NTOK / TPB2, 256, 0, stream>>>(word_inputs, word_table, char_repr,
                                              W_out, b_out, out);
}

// Round 6
// 535.111 us; speedup vs baseline: 9.2704x; 1.1332x over previous
//
#include <hip/hip_runtime.h>
#include <hip/hip_bf16.h>

#define NTOK 8192
#define SCC  16
#define CD   128
#define WD   512
#define OD   1024
#define ED   640   // WD + CD
#define TW   4     // tokens per scan workgroup

typedef __attribute__((ext_vector_type(8))) short short8;
typedef __attribute__((ext_vector_type(4))) float f32x4;

__device__ __forceinline__ unsigned short f2bf(float f) {
    union { float f; unsigned u; } v; v.f = f;
    unsigned r = v.u + 0x7FFF + ((v.u >> 16) & 1);   // RNE
    return (unsigned short)(r >> 16);
}

// ---------------------------------------------------------------------------
// Deterministic stable counting sort of tokens by length (16 bins).
// ws ints: [0..15]=hist [16..31]=base [32..47]=unused [48..48+NTOK)=order
// ---------------------------------------------------------------------------
__global__ void sort_zero(int* s) { if (threadIdx.x < 48) s[threadIdx.x] = 0; }

__global__ void sort_hist(const int* __restrict__ lengths, int* __restrict__ s) {
    const int i = blockIdx.x * 256 + threadIdx.x;
    if (i < NTOK) atomicAdd(&s[lengths[i] - 1], 1);
}

__global__ void sort_prefix(int* s) {
    if (threadIdx.x == 0) {
        int acc = 0;
        for (int b = 0; b < 16; ++b) { s[16 + b] = acc; acc += s[b]; }
    }
}

// one block per bin; ballot-based stable rank — bit-deterministic every call
__global__ __launch_bounds__(256) void sort_scatter_det(
    const int* __restrict__ lengths, int* __restrict__ s)
{
    __shared__ int wsum[4];
    __shared__ int running;
    const int b   = blockIdx.x;
    const int tid = threadIdx.x;
    if (tid == 0) running = s[16 + b];
    __syncthreads();
    for (int c0 = 0; c0 < NTOK; c0 += 256) {
        const int i = c0 + tid;
        const bool f = (lengths[i] - 1 == b);
        const unsigned long long m = __ballot(f);
        const int wv = tid >> 6;
        if ((tid & 63) == 0) wsum[wv] = __popcll(m);
        __syncthreads();
        int excl = 0;
#pragma unroll
        for (int k = 0; k < 4; ++k) if (k < wv) excl += wsum[k];
        const int lanerank = __popcll(m & ((1ull << (tid & 63)) - 1ull));
        if (f) s[48 + running + excl + lanerank] = i;
        const int tot = wsum[0] + wsum[1] + wsum[2] + wsum[3];
        __syncthreads();
        if (tid == 0) running += tot;
        __syncthreads();
    }
}

// ---------------------------------------------------------------------------
// Kernel 0: pack Wg(384x256)+Wp(128x256) fp32 -> bf16 B-fragment layout.
// lane l holds B[k=(l>>4)*8+e][n=l&15], e=0..7. n = c*128 + w*16 + (l&15).
// index: ((w*4+c)*8+kf)*64 + lane, entry = uint4 (8 bf16 along k).
// ---------------------------------------------------------------------------
__global__ __launch_bounds__(256) void pack_weights(
    const float* __restrict__ Wg, const float* __restrict__ Wp,
    uint4* __restrict__ packed)
{
    const int gid  = blockIdx.x * 256 + threadIdx.x;  // 0..16383
    const int lane = gid & 63;
    const int kf   = (gid >> 6) & 7;
    const int c    = (gid >> 9) & 3;
    const int w    = (gid >> 11) & 7;
    const int n    = c * 128 + w * 16 + (lane & 15);
    const int k0   = kf * 32 + (lane >> 4) * 8;
    const float* src = (n < 384) ? (Wg + n * 256 + k0) : (Wp + (n - 384) * 256 + k0);
    uint4 o;
    o.x = f2bf(src[0]) | ((unsigned)f2bf(src[1]) << 16);
    o.y = f2bf(src[2]) | ((unsigned)f2bf(src[3]) << 16);
    o.z = f2bf(src[4]) | ((unsigned)f2bf(src[5]) << 16);
    o.w = f2bf(src[6]) | ((unsigned)f2bf(src[7]) << 16);
    packed[gid] = o;
}

// ---------------------------------------------------------------------------
// Kernel 1: MFMA gated pyramid scan, weights register-resident.
// 4 sorted tokens/WG, 8 waves. X row r = p*4 + t (static across steps):
// D-frag element i IS token i; p = m*4 + (lane>>4). Combine writes bf16
// results straight into X (left @ row p, right @ row p-1) + masked fp32 S.
// __launch_bounds__(512,1): wreg(128)+acc(64 AGPR)+working set needs ~230
// regs; with min-waves=2 the allocator capped at 128 and spilled wreg to
// scratch in the inner loop (R5: WRITE_SIZE 206 MB, dur flat). 256-class
// still gives 2 waves/SIMD = 2 WGs/CU, so occupancy is unchanged.
// ---------------------------------------------------------------------------
__global__ __launch_bounds__(512, 1) void scan_mfma(
    const int*   __restrict__ char_ids,
    const int*   __restrict__ char_lengths,
    const float* __restrict__ char_table,
    const float* __restrict__ bg, const float* __restrict__ bp,
    const uint4* __restrict__ Wpacked,
    const int*   __restrict__ order,
    unsigned short* __restrict__ char_repr)
{
    __shared__ __align__(16) float S[TW * SCC * CD];          // 32 KB fp32 state
    __shared__ __align__(16) unsigned short X[64 * 256];      // 32 KB bf16, swizzled
    __shared__ int toksh[TW];
    __shared__ int Lsh[TW];

    const int tid  = threadIdx.x;
    const int lane = tid & 63;
    const int w    = tid >> 6;         // wave 0..7
    const int col  = lane & 15;
    const int q    = lane >> 4;        // 0..3

    if (tid < TW) {
        const int tok = order[blockIdx.x * TW + tid];
        toksh[tid] = tok;
        Lsh[tid]   = char_lengths[tok];
    }

    // ---- weights into registers: wave w's slice, 128 VGPRs, static idx ----
    short8 wreg[4][8];
#pragma unroll
    for (int c = 0; c < 4; ++c)
#pragma unroll
        for (int kf = 0; kf < 8; ++kf) {
            union { uint4 u; short8 s; } cv;
            cv.u = Wpacked[((w * 4 + c) * 8 + kf) * 64 + lane];
            wreg[c][kf] = cv.s;
        }

    const int dj = w * 16 + col;
    float biasv[4];
    biasv[0] = bg[dj];
    biasv[1] = bg[128 + dj];
    biasv[2] = bg[256 + dj];
    biasv[3] = bp[dj];

    __syncthreads();

    // init state: S[t][c][d] = char_table[ids[tok[t]][c]][d]
    for (int i = tid; i < TW * SCC * (CD / 4); i += 512) {
        const int t   = i >> 9;
        const int rem = i & 511;
        const int c   = rem >> 5;
        const int d4  = rem & 31;
        const int id  = char_ids[toksh[t] * SCC + c];
        reinterpret_cast<float4*>(S)[i] =
            reinterpret_cast<const float4*>(char_table + id * CD)[d4];
    }

    int L[TW];
#pragma unroll
    for (int t = 0; t < TW; ++t) L[t] = Lsh[t];
    const int maxL = max(max(L[0], L[1]), max(L[2], L[3]));

    __syncthreads();

    // init X once: row r=p*4+t = [S[t][p] | S[t][p+1]] bf16 (contiguous 256f),
    // rows with p=15 zero-filled (never valid, keeps MFMA inputs finite).
    for (int i = tid; i < 64 * 128; i += 512) {
        const int r  = i >> 7;
        const int ku = i & 127;
        const int p  = r >> 2;
        const int t  = r & 3;
        unsigned u = 0u;
        if (p < 15) {
            const float2 v = reinterpret_cast<const float2*>(S + t * 2048 + p * 128)[ku];
            u = f2bf(v.x) | ((unsigned)f2bf(v.y) << 16);
        }
        int baddr = (r << 9) + (ku << 2);
        baddr ^= (r & 7) << 4;
        *reinterpret_cast<unsigned*>(reinterpret_cast<char*>(X) + baddr) = u;
    }
    __syncthreads();

    for (int len = 1; len < maxL; ++len) {
        const int Amax   = maxL - len;
        const int mfrags = (4 * Amax + 15) >> 4;

        f32x4 acc[4][4];   // [m-frag][chunk]
#pragma unroll
        for (int m = 0; m < 4; ++m)
#pragma unroll
            for (int c = 0; c < 4; ++c) acc[m][c] = (f32x4){0.f, 0.f, 0.f, 0.f};

        // ---- MFMA phase: A from LDS X, B from registers ----
#pragma unroll
        for (int kf = 0; kf < 8; ++kf) {
#pragma unroll
            for (int m = 0; m < 4; ++m) {
                if (m < mfrags) {
                    const int row = m * 16 + col;
                    int baddr = (row << 9) + (kf << 6) + (q << 4);
                    baddr ^= (row & 7) << 4;
                    const short8 a = *reinterpret_cast<const short8*>(
                        reinterpret_cast<const char*>(X) + baddr);
#pragma unroll
                    for (int c = 0; c < 4; ++c)
                        acc[m][c] = __builtin_amdgcn_mfma_f32_16x16x32_bf16(
                            a, wreg[c][kf], acc[m][c], 0, 0, 0);
                }
            }
        }

        // ---- combine: lane-local softmax + convex mix. t = i, p = m*4+q ----
#pragma unroll
        for (int m = 0; m < 4; ++m) {
            if (m < mfrags) {
                const int p = m * 4 + q;
#pragma unroll
                for (int i = 0; i < 4; ++i) {
                    const float g0 = acc[m][0][i] + biasv[0];
                    const float g1 = acc[m][1][i] + biasv[1];
                    const float g2 = acc[m][2][i] + biasv[2];
                    const float z  = acc[m][3][i] + biasv[3];
                    const float mx = fmaxf(fmaxf(g0, g1), g2);
                    const float e0 = __expf(g0 - mx);
                    const float e1 = __expf(g1 - mx);
                    const float e2 = __expf(g2 - mx);
                    const float left  = S[i * 2048 + p * 128 + dj];
                    const float right = S[i * 2048 + (p + 1) * 128 + dj];
                    acc[m][0][i] = (e0 * left + e1 * right + e2 * z) / (e0 + e1 + e2);
                }
            }
        }
        __syncthreads();   // all X-reads (MFMA) and S-reads (combine) done

        // ---- write phase: masked fp32 S + bf16 X (left @ p, right @ p-1) ----
#pragma unroll
        for (int m = 0; m < 4; ++m) {
            if (m < mfrags) {
                const int p = m * 4 + q;
#pragma unroll
                for (int i = 0; i < 4; ++i) {
                    const float val = acc[m][0][i];
                    if (p < L[i] - len) S[i * 2048 + p * 128 + dj] = val;
                    const unsigned short bv = f2bf(val);
                    const int rl = m * 16 + q * 4 + i;          // row p*4+i
                    int bl = (rl << 9) + (dj << 1);
                    bl ^= (rl & 7) << 4;
                    *reinterpret_cast<unsigned short*>(
                        reinterpret_cast<char*>(X) + bl) = bv;
                    if (p >= 1) {
                        const int rr = rl - 4;                  // row (p-1)*4+i
                        int br = (rr << 9) + 256 + (dj << 1);
                        br ^= (rr & 7) << 4;
                        *reinterpret_cast<unsigned short*>(
                            reinterpret_cast<char*>(X) + br) = bv;
                    }
                }
            }
        }
        __syncthreads();
    }

    // char representation = S[t][0][:], stored bf16
    for (int i = tid; i < TW * CD; i += 512) {
        const int t = i >> 7, d = i & 127;
        char_repr[toksh[t] * CD + d] = f2bf(S[t * 2048 + d]);
    }
}

// ---------------------------------------------------------------------------
// Kernel 2: out[t][j] = b_out[j] + emb[t] . W_out[j]
// ---------------------------------------------------------------------------
#define TPB2 16

__global__ __launch_bounds__(256) void out_gemm(
    const int*   __restrict__ word_inputs,
    const float* __restrict__ word_table,
    const unsigned short* __restrict__ char_repr,   // bf16 bits
    const float* __restrict__ W_out,
    const float* __restrict__ b_out,
    float*       __restrict__ out)
{
    __shared__ __align__(16) float E[TPB2 * ED];  // 40 KB

    const int tg  = blockIdx.x * TPB2;
    const int tid = threadIdx.x;

    for (int i = tid; i < TPB2 * WD; i += 256) {
        const int tl = i >> 9, k = i & 511;
        E[tl * ED + k] = word_table[(size_t)word_inputs[tg + tl] * WD + k];
    }
    for (int i = tid; i < TPB2 * CD; i += 256) {
        const int tl = i >> 7, k = i & 127;
        union { unsigned u; float f; } qq;
        qq.u = ((unsigned)char_repr[(tg + tl) * CD + k]) << 16;
        E[tl * ED + WD + k] = qq.f;
    }
    __syncthreads();

    const int j0 = tid * 4;
    float acc[TPB2][4];
#pragma unroll
    for (int tl = 0; tl < TPB2; ++tl)
#pragma unroll
        for (int jj = 0; jj < 4; ++jj) acc[tl][jj] = 0.f;

#pragma unroll 2
    for (int kc = 0; kc < ED / 4; ++kc) {
        const int k = kc * 4;
        float4 wr[4];
#pragma unroll
        for (int jj = 0; jj < 4; ++jj)
            wr[jj] = *reinterpret_cast<const float4*>(W_out + (size_t)(j0 + jj) * ED + k);
#pragma unroll
        for (int tl = 0; tl < TPB2; ++tl) {
            const float4 e = *reinterpret_cast<const float4*>(E + tl * ED + k);
#pragma unroll
            for (int jj = 0; jj < 4; ++jj) {
                acc[tl][jj] = fmaf(wr[jj].x, e.x, acc[tl][jj]);
                acc[tl][jj] = fmaf(wr[jj].y, e.y, acc[tl][jj]);
                acc[tl][jj] = fmaf(wr[jj].z, e.z, acc[tl][jj]);
                acc[tl][jj] = fmaf(wr[jj].w, e.w, acc[tl][jj]);
            }
        }
    }

    const float4 bb = *reinterpret_cast<const float4*>(b_out + j0);
#pragma unroll
    for (int tl = 0; tl < TPB2; ++tl) {
        float4 r;
        r.x = acc[tl][0] + bb.x;
        r.y = acc[tl][1] + bb.y;
        r.z = acc[tl][2] + bb.z;
        r.w = acc[tl][3] + bb.w;
        *reinterpret_cast<float4*>(out + (size_t)(tg + tl) * OD + j0) = r;
    }
}

// ---------------------------------------------------------------------------

extern "C" void kernel_launch(void* const* d_in, const int* in_sizes, int n_in,
                              void* d_out, int out_size, void* d_ws, size_t ws_size,
                              hipStream_t stream)
{
    const int*   word_inputs  = (const int*)  d_in[0];
    const int*   char_ids     = (const int*)  d_in[1];
    const int*   char_lengths = (const int*)  d_in[2];
    const float* word_table   = (const float*)d_in[3];
    const float* char_table   = (const float*)d_in[4];
    const float* Wg           = (const float*)d_in[5];
    const float* bg           = (const float*)d_in[6];
    const float* Wp           = (const float*)d_in[7];
    const float* bp           = (const float*)d_in[8];
    const float* W_out        = (const float*)d_in[9];
    const float* b_out        = (const float*)d_in[10];

    float* out = (float*)d_out;
    unsigned short* char_repr = (unsigned short*)d_ws;              // 2 MB bf16
    uint4* Wpacked = (uint4*)((char*)d_ws + 2 * 1024 * 1024);       // 256 KB
    int*   sortbuf = (int*)((char*)d_ws + 2 * 1024 * 1024 + 256 * 1024);
    const int* order = sortbuf + 48;

    pack_weights<<<64, 256, 0, stream>>>(Wg, Wp, Wpacked);
    sort_zero<<<1, 64, 0, stream>>>(sortbuf);
    sort_hist<<<NTOK / 256, 256, 0, stream>>>(char_lengths, sortbuf);
    sort_prefix<<<1, 64, 0, stream>>>(sortbuf);
    sort_scatter_det<<<16, 256, 0, stream>>>(char_lengths, sortbuf);

    scan_mfma<<<NTOK / TW, 512, 0, stream>>>(char_ids, char_lengths, char_table,
                                             bg, bp, Wpacked, order, char_repr);
    out_gemm<<<NTOK / TPB2, 256, 0, stream>>>(word_inputs, word_table, char_repr,
                                              W_out, b_out, out);
}